// Round 1
// baseline (165.400 us; speedup 1.0000x reference)
//
#include <hip/hip_runtime.h>
#include <climits>
#include <math.h>

// ---------------------------------------------------------------------------
// DescriptorModel: neutron-weighted G(r), T(r), S(Q), tetrahedral q over Si.
// N=4096, nbins=200, nq=500. Outputs concatenated: [G_r(200), T_r(200),
// S_Q(500), q_tet(1)] = 901 fp32.
// ---------------------------------------------------------------------------

#define B_SI_F 4.1491f
#define B_O_F  5.803f
#define CUTOFF_F 3.5f
#define NCOPIES 16

// ws float layout:
//  [0..8]   inv(cell) row-major
//  [9]      w_scale = 1/mean(b)^2
//  [10]     rho = N/V
//  [12]     sum(q_i * vf)
//  [13]     sum(vf)
//  [16 .. 16+NCOPIES*nbins)        histogram copies
//  [WS_POS4 .. WS_POS4+4N)         packed float4 (x,y,z,b) per atom
#define WS_HIST 16
#define WS_POS4 4096   // requires 16 + NCOPIES*nbins <= 4096 (3216 for nbins=200)

__device__ __forceinline__ bool dless(float da, int ia, float db, int ib) {
    return (da < db) || (da == db && ia < ib);
}

// ---------------------------------------------------------------------------
__global__ void k_init(const float* __restrict__ cell,
                       const float* __restrict__ pos,
                       const int* __restrict__ species,
                       float* __restrict__ ws, int N, int nbins) {
    const int tid = threadIdx.x;

    // zero histogram copies
    for (int i = tid; i < NCOPIES * nbins; i += blockDim.x)
        ws[WS_HIST + i] = 0.0f;

    // pack (x,y,z,b) float4 per atom
    float4* p4 = (float4*)(ws + WS_POS4);
    for (int j = tid; j < N; j += blockDim.x) {
        float b = (species[j] == 0) ? B_SI_F : B_O_F;
        p4[j] = make_float4(pos[3*j], pos[3*j+1], pos[3*j+2], b);
    }

    // count Si for mean_b
    __shared__ int cnt[256];
    int c = 0;
    for (int i = tid; i < N; i += blockDim.x) c += (species[i] == 0) ? 1 : 0;
    cnt[tid] = c;
    __syncthreads();
    for (int s = 128; s > 0; s >>= 1) {
        if (tid < s) cnt[tid] += cnt[tid + s];
        __syncthreads();
    }

    if (tid == 0) {
        int nSi = cnt[0];
        double m[9];
        #pragma unroll
        for (int i = 0; i < 9; ++i) m[i] = (double)cell[i];
        double det = m[0]*(m[4]*m[8]-m[5]*m[7])
                   - m[1]*(m[3]*m[8]-m[5]*m[6])
                   + m[2]*(m[3]*m[7]-m[4]*m[6]);
        double inv[9];
        inv[0] =  (m[4]*m[8]-m[5]*m[7])/det;
        inv[1] = -(m[1]*m[8]-m[2]*m[7])/det;
        inv[2] =  (m[1]*m[5]-m[2]*m[4])/det;
        inv[3] = -(m[3]*m[8]-m[5]*m[6])/det;
        inv[4] =  (m[0]*m[8]-m[2]*m[6])/det;
        inv[5] = -(m[0]*m[5]-m[2]*m[3])/det;
        inv[6] =  (m[3]*m[7]-m[4]*m[6])/det;
        inv[7] = -(m[0]*m[7]-m[1]*m[6])/det;
        inv[8] =  (m[0]*m[4]-m[1]*m[3])/det;
        #pragma unroll
        for (int i = 0; i < 9; ++i) ws[i] = (float)inv[i];
        float mean_b = ((float)nSi * B_SI_F + (float)(N - nSi) * B_O_F) / (float)N;
        ws[9]  = 1.0f / (mean_b * mean_b);
        ws[10] = (float)N / (float)fabs(det);
        ws[12] = 0.0f;
        ws[13] = 0.0f;
    }
}

// ---------------------------------------------------------------------------
// One block per atom i. 256 threads sweep j. LDS histogram + top-4 O list.
__global__ __launch_bounds__(256) void k_pairs(const float* __restrict__ cellm,
                                               const float* __restrict__ rbins,
                                               float* __restrict__ ws,
                                               int N, int nbins) {
    const int i = blockIdx.x;
    const int tid = threadIdx.x;

    __shared__ float shist[512];
    __shared__ float sd[256 * 4];
    __shared__ int   si[256 * 4];

    for (int t = tid; t < nbins; t += blockDim.x) shist[t] = 0.0f;

    // cell + inverse (uniform)
    const float ci0 = ws[0], ci1 = ws[1], ci2 = ws[2];
    const float ci3 = ws[3], ci4 = ws[4], ci5 = ws[5];
    const float ci6 = ws[6], ci7 = ws[7], ci8 = ws[8];
    const float c0 = cellm[0], c1 = cellm[1], c2 = cellm[2];
    const float c3 = cellm[3], c4 = cellm[4], c5 = cellm[5];
    const float c6 = cellm[6], c7 = cellm[7], c8 = cellm[8];
    const float w_scale = ws[9];
    const float r0 = rbins[0];
    const float dr = rbins[1] - rbins[0];

    const float4* __restrict__ p4 = (const float4*)(ws + WS_POS4);
    const float4 pi_ = p4[i];
    const float xi = pi_.x, yi = pi_.y, zi = pi_.z;
    const float b_i = pi_.w;
    const bool is_si = (b_i == B_SI_F);

    float d4[4]  = {1e6f, 1e6f, 1e6f, 1e6f};
    int   id4[4] = {INT_MAX, INT_MAX, INT_MAX, INT_MAX};

    __syncthreads();

    for (int j = tid; j < N; j += blockDim.x) {
        if (j == i) continue;
        const float4 pj = p4[j];
        float dx = xi - pj.x, dy = yi - pj.y, dz = zi - pj.z;
        float f0 = dx*ci0 + dy*ci3 + dz*ci6;
        float f1 = dx*ci1 + dy*ci4 + dz*ci7;
        float f2 = dx*ci2 + dy*ci5 + dz*ci8;
        f0 -= rintf(f0);  f1 -= rintf(f1);  f2 -= rintf(f2);
        float ex = f0*c0 + f1*c3 + f2*c6;
        float ey = f0*c1 + f1*c4 + f2*c7;
        float ez = f0*c2 + f1*c5 + f2*c8;
        float d2 = ex*ex + ey*ey + ez*ez;
        float dist = sqrtf(d2);

        // --- cloud-in-cell histogram ---
        float x  = (dist - r0) / dr;
        float fl = floorf(x);
        int   i0 = (int)fl;
        if (i0 >= 0 && i0 < nbins - 1) {
            float w = b_i * pj.w * w_scale;
            float f = x - fl;
            atomicAdd(&shist[i0],     w * (1.0f - f));
            atomicAdd(&shist[i0 + 1], w * f);
        }

        // --- top-4 nearest O neighbours (Si rows only) ---
        if (is_si && pj.w == B_O_F) {
            if (dless(dist, j, d4[3], id4[3])) {
                d4[3] = dist; id4[3] = j;
                #pragma unroll
                for (int k = 3; k > 0; --k) {
                    if (dless(d4[k], id4[k], d4[k-1], id4[k-1])) {
                        float td = d4[k]; d4[k] = d4[k-1]; d4[k-1] = td;
                        int   ti = id4[k]; id4[k] = id4[k-1]; id4[k-1] = ti;
                    }
                }
            }
        }
    }
    __syncthreads();

    // flush LDS histogram → one of NCOPIES global copies
    {
        float* gh = ws + WS_HIST + (size_t)(i % NCOPIES) * nbins;
        for (int t = tid; t < nbins; t += blockDim.x) {
            float h = shist[t];
            if (h != 0.0f) atomicAdd(&gh[t], h);
        }
    }

    // --- block-wide top-4 merge + q_i (Si rows; block-uniform branch) ---
    if (is_si) {
        #pragma unroll
        for (int k = 0; k < 4; ++k) { sd[4*tid+k] = d4[k]; si[4*tid+k] = id4[k]; }
        __syncthreads();
        for (int s = 128; s > 0; s >>= 1) {
            if (tid < s) {
                float a[4], b[4], o[4];
                int  ai[4], bi[4], oi[4];
                #pragma unroll
                for (int k = 0; k < 4; ++k) {
                    a[k] = sd[4*tid+k];      ai[k] = si[4*tid+k];
                    b[k] = sd[4*(tid+s)+k];  bi[k] = si[4*(tid+s)+k];
                }
                int pa = 0, pb = 0;
                #pragma unroll
                for (int k = 0; k < 4; ++k) {
                    bool ta = dless(a[pa], ai[pa], b[pb], bi[pb]);
                    o[k]  = ta ? a[pa]  : b[pb];
                    oi[k] = ta ? ai[pa] : bi[pb];
                    pa += ta ? 1 : 0;
                    pb += ta ? 0 : 1;
                }
                #pragma unroll
                for (int k = 0; k < 4; ++k) { sd[4*tid+k] = o[k]; si[4*tid+k] = oi[k]; }
            }
            __syncthreads();
        }

        if (tid == 0) {
            float dd[4]; int jj[4];
            #pragma unroll
            for (int k = 0; k < 4; ++k) { dd[k] = sd[k]; jj[k] = si[k]; }
            if (dd[3] < CUTOFF_F) {   // vf = 1
                float ux[4], uy[4], uz[4];
                #pragma unroll
                for (int k = 0; k < 4; ++k) {
                    const float4 pj = p4[jj[k]];
                    float dx = xi - pj.x, dy = yi - pj.y, dz = zi - pj.z;
                    float f0 = dx*ci0 + dy*ci3 + dz*ci6;
                    float f1 = dx*ci1 + dy*ci4 + dz*ci7;
                    float f2 = dx*ci2 + dy*ci5 + dz*ci8;
                    f0 -= rintf(f0);  f1 -= rintf(f1);  f2 -= rintf(f2);
                    float ex = f0*c0 + f1*c3 + f2*c6;
                    float ey = f0*c1 + f1*c4 + f2*c7;
                    float ez = f0*c2 + f1*c5 + f2*c8;
                    ux[k] = ex / dd[k];
                    uy[k] = ey / dd[k];
                    uz[k] = ez / dd[k];
                }
                float s2 = 0.0f;
                #pragma unroll
                for (int k = 0; k < 4; ++k)
                    #pragma unroll
                    for (int l = k + 1; l < 4; ++l) {
                        float cs = ux[k]*ux[l] + uy[k]*uy[l] + uz[k]*uz[l];
                        float t  = cs + (1.0f / 3.0f);
                        s2 += t * t;
                    }
                float qi = 1.0f - 0.375f * s2;
                atomicAdd(&ws[12], qi);
                atomicAdd(&ws[13], 1.0f);
            }
        }
    }
}

// ---------------------------------------------------------------------------
__global__ void k_finalize(const float* __restrict__ ws,
                           const float* __restrict__ rbins,
                           const float* __restrict__ qbins,
                           float* __restrict__ out,
                           int N, int nbins, int nq) {
    __shared__ float G[512];
    const int tid = threadIdx.x;
    const float rho = ws[10];
    const float dr  = rbins[1] - rbins[0];
    const float FOURPI = 4.0f * 3.14159265358979323846f;

    for (int t = tid; t < nbins; t += blockDim.x) {
        float h = 0.0f;
        for (int c = 0; c < NCOPIES; ++c) h += ws[WS_HIST + c * nbins + t];
        float r = rbins[t];
        float shell = FOURPI * r * r * dr;
        float g = h / ((float)N * rho * shell);
        G[t] = g;
        if (blockIdx.x == 0) {
            out[t] = g;
            out[nbins + t] = FOURPI * rho * r * g;
        }
    }
    __syncthreads();

    int q = blockIdx.x * blockDim.x + tid;
    if (q < nq) {
        float qq = qbins[q];
        float s = 0.0f;
        for (int t = 0; t < nbins; ++t) {
            float r  = rbins[t];
            float qr = qq * r;
            float sc = sinf(qr) / qr;          // jnp.sinc(qr/pi)
            s += r * r * (G[t] - 1.0f) * sc;
        }
        out[2 * nbins + q] = 1.0f + FOURPI * rho * dr * s;
    }
    if (blockIdx.x == 0 && tid == 0) {
        out[2 * nbins + nq] = ws[12] / fmaxf(ws[13], 1.0f);
    }
}

// ---------------------------------------------------------------------------
extern "C" void kernel_launch(void* const* d_in, const int* in_sizes, int n_in,
                              void* d_out, int out_size, void* d_ws, size_t ws_size,
                              hipStream_t stream) {
    const float* pos     = (const float*)d_in[0];
    const float* cell    = (const float*)d_in[1];
    const float* rbins   = (const float*)d_in[2];
    const float* qbins   = (const float*)d_in[3];
    const int*   species = (const int*)d_in[4];
    float* out = (float*)d_out;
    float* ws  = (float*)d_ws;

    const int N     = in_sizes[4];
    const int nbins = in_sizes[2];
    const int nq    = in_sizes[3];

    k_init<<<1, 256, 0, stream>>>(cell, pos, species, ws, N, nbins);
    k_pairs<<<N, 256, 0, stream>>>(cell, rbins, ws, N, nbins);
    k_finalize<<<(nq + 255) / 256, 256, 0, stream>>>(ws, rbins, qbins, out, N, nbins, nq);
}